// Round 7
// baseline (498.623 us; speedup 1.0000x reference)
//
#include <hip/hip_runtime.h>
#include <hip/hip_bf16.h>

#define N 8192
#define DIN 256
#define DOUT 64
#define JSPLIT 16
#define JSPAN (N / JSPLIT)      // 512
#define NITILES (N / 64)        // 128
#define NWORDS (N / 64)         // 128 u64 mask words per row
#define LEAKY 0.2f

typedef __attribute__((ext_vector_type(8))) short bf16x8;
typedef __attribute__((ext_vector_type(4))) float f32x4;

// workspace layout (aligned slices)
#define OFF_ZT   ((size_t)0)                               // DOUT*N*2  = 1 MiB
#define OFF_SI   (OFF_ZT + (size_t)DOUT * N * 2)           // N*4
#define OFF_SJ   (OFF_SI + (size_t)N * 4)                  // N*4
#define OFF_MAX  (OFF_SJ + (size_t)N * 4)                  // 256 (2 uints used)
#define OFF_MASK (OFF_MAX + 256)                           // N*N/8 = 8 MiB
#define OFF_PDEN (OFF_MASK + (size_t)N * N / 8)            // JSPLIT*N*4
#define OFF_PNUM (OFF_PDEN + (size_t)JSPLIT * N * 4)       // JSPLIT*N*DOUT*4 = 32 MiB

static __device__ __forceinline__ short f2bf(float f) {
  union { __hip_bfloat16 h; short s; } u;
  u.h = __float2bfloat16(f);
  return u.s;
}

// monotone float<->unsigned key for atomicMax (poison 0xAAAAAAAA decodes to
// +3.03e-13, provably below max of 8192 ~N(0,1) samples -> no init needed)
static __device__ __forceinline__ unsigned fkey(float f) {
  int b = __float_as_int(f);
  return (b < 0) ? ~(unsigned)b : ((unsigned)b | 0x80000000u);
}
static __device__ __forceinline__ float fdec(unsigned k) {
  int b = (k & 0x80000000u) ? (int)(k & 0x7fffffffu) : (int)~k;
  return __int_as_float(b);
}

// ---- kernel 1: z = x@W ; si = z@a1 ; sj = z@a2 ; zT(bf16) ; max-reduce -----
__global__ __launch_bounds__(256) void gat_proj(
    const float* __restrict__ x, const float* __restrict__ W,
    const float* __restrict__ a, __hip_bfloat16* __restrict__ zT,
    float* __restrict__ si, float* __restrict__ sj,
    unsigned* __restrict__ mx) {
  __shared__ float wmx[4][2];
  const int lane = threadIdx.x & 63;
  const int wave = threadIdx.x >> 6;
  const int rowbase = blockIdx.x * 16 + wave * 4;  // 4 rows per wave, lane = col
  float acc[4] = {0.f, 0.f, 0.f, 0.f};
  for (int k = 0; k < DIN; k += 4) {
    const float w0 = W[(k + 0) * DOUT + lane];
    const float w1 = W[(k + 1) * DOUT + lane];
    const float w2 = W[(k + 2) * DOUT + lane];
    const float w3 = W[(k + 3) * DOUT + lane];
#pragma unroll
    for (int r = 0; r < 4; ++r) {
      const float4 xv = *reinterpret_cast<const float4*>(&x[(size_t)(rowbase + r) * DIN + k]);
      acc[r] += xv.x * w0 + xv.y * w1 + xv.z * w2 + xv.w * w3;
    }
  }
  const float a1l = a[lane];
  const float a2l = a[DOUT + lane];
  float wm1 = -1e30f, wm2 = -1e30f;
#pragma unroll
  for (int r = 0; r < 4; ++r) {
    const int row = rowbase + r;
    zT[(size_t)lane * N + row] = __float2bfloat16(acc[r]);
    float v1 = acc[r] * a1l;
    float v2 = acc[r] * a2l;
#pragma unroll
    for (int m = 1; m < 64; m <<= 1) {
      v1 += __shfl_xor(v1, m);
      v2 += __shfl_xor(v2, m);
    }
    if (lane == 0) { si[row] = v1; sj[row] = v2; }
    wm1 = fmaxf(wm1, v1);
    wm2 = fmaxf(wm2, v2);
  }
  if (lane == 0) { wmx[wave][0] = wm1; wmx[wave][1] = wm2; }
  __syncthreads();
  if (threadIdx.x == 0) {
    float M1 = fmaxf(fmaxf(wmx[0][0], wmx[1][0]), fmaxf(wmx[2][0], wmx[3][0]));
    float M2 = fmaxf(fmaxf(wmx[0][1], wmx[1][1]), fmaxf(wmx[2][1], wmx[3][1]));
    atomicMax(mx + 0, fkey(M1));
    atomicMax(mx + 1, fkey(M2));
  }
}

// ---- kernel 2: adj (int32) -> bitmask (u64 per 64 consecutive j) -----------
// Perfectly coalesced: each lane reads one dword (256B/inst per wave), ballot
// packs 64 j's into one u64. The ONLY HBM-heavy kernel; everything downstream
// is cache-resident. 2048 blocks x 4 waves x 4 words/iter x 32 iters = 1M words.
__global__ __launch_bounds__(256) void gat_compress(
    const int* __restrict__ adj, unsigned long long* __restrict__ mask) {
  const int lane = threadIdx.x & 63;
  const size_t wid = (size_t)blockIdx.x * 4 + (threadIdx.x >> 6);
  const size_t nw = (size_t)gridDim.x * 4;
  const size_t total = (size_t)N * N / 64;  // 1,048,576 words
  for (size_t w = wid * 4; w < total; w += nw * 4) {
    const int v0 = adj[(w << 6) | lane];
    const int v1 = adj[((w + 1) << 6) | lane];
    const int v2 = adj[((w + 2) << 6) | lane];
    const int v3 = adj[((w + 3) << 6) | lane];
    const unsigned long long m0 = __ballot(v0 > 0);
    const unsigned long long m1 = __ballot(v1 > 0);
    const unsigned long long m2 = __ballot(v2 > 0);
    const unsigned long long m3 = __ballot(v3 > 0);
    if (lane == 0) {
      mask[w] = m0; mask[w + 1] = m1; mask[w + 2] = m2; mask[w + 3] = m3;
    }
  }
}

// ---- kernel 3: fused mask+exp + partial P@z (MFMA), all-cache-resident -----
// grid = NITILES*JSPLIT = 2048 blocks of 256 (4 waves x 16 rows). All loads
// (mask 8MiB, sj 32KB, zT 1MiB) are L2-resident -> latency-benign at high
// occupancy. P built directly in the 16x16x32 A-fragment layout.
__global__ __launch_bounds__(256, 6) void gat_main(
    const unsigned long long* __restrict__ mask, const float* __restrict__ si,
    const float* __restrict__ sj, const __hip_bfloat16* __restrict__ zT,
    const unsigned* __restrict__ mx, float* __restrict__ pnum,
    float* __restrict__ pden) {
  const int lane = threadIdx.x & 63;
  const int wave = threadIdx.x >> 6;
  const int itile = blockIdx.x % NITILES;
  const int jchunk = blockIdx.x / NITILES;
  const int r16 = lane & 15;
  const int kgrp = lane >> 4;
  const int row = itile * 64 + wave * 16 + r16;

  const float tC = fdec(mx[0]) + fdec(mx[1]);
  const float C = tC > 0.f ? tC : LEAKY * tC;
  const float sir = si[row];

  const unsigned long long* __restrict__ mp =
      mask + (size_t)row * NWORDS + (jchunk * JSPAN) / 64;  // 8 words
  const float* __restrict__ sp = sj + jchunk * JSPAN + kgrp * 8;
  const __hip_bfloat16* __restrict__ zp =
      zT + (size_t)r16 * N + jchunk * JSPAN + kgrp * 8;

  f32x4 acc0 = {0.f, 0.f, 0.f, 0.f};
  f32x4 acc1 = acc0, acc2 = acc0, acc3 = acc0;
  float dacc = 0.f;

#pragma unroll 1
  for (int w = 0; w < JSPAN / 64; ++w) {  // 8 mask words, 2 K-steps each
    const unsigned long long mword = mp[w];
#pragma unroll
    for (int sub = 0; sub < 2; ++sub) {
      const unsigned bits = (unsigned)(mword >> (sub * 32 + kgrp * 8)) & 0xffu;

      const bf16x8 b0 = *reinterpret_cast<const bf16x8*>(zp);
      const bf16x8 b1 = *reinterpret_cast<const bf16x8*>(zp + 16 * N);
      const bf16x8 b2 = *reinterpret_cast<const bf16x8*>(zp + 32 * N);
      const bf16x8 b3 = *reinterpret_cast<const bf16x8*>(zp + 48 * N);
      const float4 s0 = *reinterpret_cast<const float4*>(sp);
      const float4 s1 = *reinterpret_cast<const float4*>(sp + 4);
      zp += 32;
      sp += 32;

      float p0, p1, p2, p3, p4, p5, p6, p7, t;
      t = sir + s0.x; t = fmaxf(t, LEAKY * t); p0 = (bits & 1u)   ? __expf(t - C) : 0.f;
      t = sir + s0.y; t = fmaxf(t, LEAKY * t); p1 = (bits & 2u)   ? __expf(t - C) : 0.f;
      t = sir + s0.z; t = fmaxf(t, LEAKY * t); p2 = (bits & 4u)   ? __expf(t - C) : 0.f;
      t = sir + s0.w; t = fmaxf(t, LEAKY * t); p3 = (bits & 8u)   ? __expf(t - C) : 0.f;
      t = sir + s1.x; t = fmaxf(t, LEAKY * t); p4 = (bits & 16u)  ? __expf(t - C) : 0.f;
      t = sir + s1.y; t = fmaxf(t, LEAKY * t); p5 = (bits & 32u)  ? __expf(t - C) : 0.f;
      t = sir + s1.z; t = fmaxf(t, LEAKY * t); p6 = (bits & 64u)  ? __expf(t - C) : 0.f;
      t = sir + s1.w; t = fmaxf(t, LEAKY * t); p7 = (bits & 128u) ? __expf(t - C) : 0.f;

      dacc += ((p0 + p1) + (p2 + p3)) + ((p4 + p5) + (p6 + p7));

      bf16x8 afr;
      afr[0] = f2bf(p0); afr[1] = f2bf(p1); afr[2] = f2bf(p2); afr[3] = f2bf(p3);
      afr[4] = f2bf(p4); afr[5] = f2bf(p5); afr[6] = f2bf(p6); afr[7] = f2bf(p7);

      acc0 = __builtin_amdgcn_mfma_f32_16x16x32_bf16(afr, b0, acc0, 0, 0, 0);
      acc1 = __builtin_amdgcn_mfma_f32_16x16x32_bf16(afr, b1, acc1, 0, 0, 0);
      acc2 = __builtin_amdgcn_mfma_f32_16x16x32_bf16(afr, b2, acc2, 0, 0, 0);
      acc3 = __builtin_amdgcn_mfma_f32_16x16x32_bf16(afr, b3, acc3, 0, 0, 0);
    }
  }

  // denominator: combine the 4 k-groups holding the same row
  dacc += __shfl_xor(dacc, 16);
  dacc += __shfl_xor(dacc, 32);
  if (lane < 16) pden[(size_t)jchunk * N + row] = dacc;

  // C/D layout (16x16x32): col = lane&15, row = (lane>>4)*4 + reg
  float* np = pnum + ((size_t)jchunk * N + (size_t)itile * 64 + wave * 16) * DOUT;
  const f32x4 accs[4] = {acc0, acc1, acc2, acc3};
#pragma unroll
  for (int dt = 0; dt < 4; ++dt) {
#pragma unroll
    for (int r = 0; r < 4; ++r) {
      np[(kgrp * 4 + r) * DOUT + dt * 16 + r16] = accs[dt][r];
    }
  }
}

// ---- kernel 4: combine partials, divide, bias, relu ------------------------
__global__ __launch_bounds__(256) void gat_combine(
    const float* __restrict__ pnum, const float* __restrict__ pden,
    const float* __restrict__ b, float* __restrict__ out) {
  const int idx = blockIdx.x * 256 + threadIdx.x;
  const int row = idx >> 6;
  const int d = idx & 63;
  float num = 0.f, den = 0.f;
#pragma unroll
  for (int s = 0; s < JSPLIT; ++s) num += pnum[(size_t)s * N * DOUT + idx];
#pragma unroll
  for (int s = 0; s < JSPLIT; ++s) den += pden[(size_t)s * N + row];
  const float o = num / den + b[d];
  out[idx] = o > 0.f ? o : 0.f;
}

extern "C" void kernel_launch(void* const* d_in, const int* in_sizes, int n_in,
                              void* d_out, int out_size, void* d_ws, size_t ws_size,
                              hipStream_t stream) {
  const float* x = (const float*)d_in[0];
  const int* adj = (const int*)d_in[1];
  const float* W = (const float*)d_in[2];
  const float* a = (const float*)d_in[3];
  const float* b = (const float*)d_in[4];
  float* out = (float*)d_out;
  char* ws = (char*)d_ws;

  __hip_bfloat16* zT = (__hip_bfloat16*)(ws + OFF_ZT);
  float* si = (float*)(ws + OFF_SI);
  float* sj = (float*)(ws + OFF_SJ);
  unsigned* mx = (unsigned*)(ws + OFF_MAX);
  unsigned long long* mask = (unsigned long long*)(ws + OFF_MASK);
  float* pden = (float*)(ws + OFF_PDEN);
  float* pnum = (float*)(ws + OFF_PNUM);

  gat_proj<<<dim3(N / 16), dim3(256), 0, stream>>>(x, W, a, zT, si, sj, mx);
  gat_compress<<<dim3(2048), dim3(256), 0, stream>>>(adj, mask);
  gat_main<<<dim3(NITILES * JSPLIT), dim3(256), 0, stream>>>(mask, si, sj, zT, mx,
                                                             pnum, pden);
  gat_combine<<<dim3((N * DOUT) / 256), dim3(256), 0, stream>>>(pnum, pden, b, out);
}

// Round 9
// 480.889 us; speedup vs baseline: 1.0369x; 1.0369x over previous
//
#include <hip/hip_runtime.h>
#include <hip/hip_bf16.h>

#define N 8192
#define DIN 256
#define DOUT 64
#define JSPLIT 16
#define JSPAN (N / JSPLIT)      // 512
#define NITILES (N / 64)        // 128
#define LEAKY 0.2f

typedef __attribute__((ext_vector_type(8))) short bf16x8;
typedef __attribute__((ext_vector_type(4))) float f32x4;

// workspace layout (aligned slices)
#define OFF_ZT   ((size_t)0)                               // DOUT*N*2  = 1 MiB
#define OFF_SI   (OFF_ZT + (size_t)DOUT * N * 2)           // N*4
#define OFF_SJ   (OFF_SI + (size_t)N * 4)                  // N*4
#define OFF_MAX  (OFF_SJ + (size_t)N * 4)                  // 256 (2 uints used)
#define OFF_PDEN (OFF_MAX + 256)                           // JSPLIT*N*4
#define OFF_PNUM (OFF_PDEN + (size_t)JSPLIT * N * 4)       // JSPLIT*N*DOUT*4 = 32 MiB

static __device__ __forceinline__ short f2bf(float f) {
  union { __hip_bfloat16 h; short s; } u;
  u.h = __float2bfloat16(f);
  return u.s;
}

// monotone float<->unsigned key for atomicMax (poison 0xAAAAAAAA decodes to
// +3.03e-13, provably below max of 8192 ~N(0,1) samples -> no init needed)
static __device__ __forceinline__ unsigned fkey(float f) {
  int b = __float_as_int(f);
  return (b < 0) ? ~(unsigned)b : ((unsigned)b | 0x80000000u);
}
static __device__ __forceinline__ float fdec(unsigned k) {
  int b = (k & 0x80000000u) ? (int)(k & 0x7fffffffu) : (int)~k;
  return __int_as_float(b);
}

// ---- kernel 1: z = x@W ; si = z@a1 ; sj = z@a2 ; zT(bf16) ; max-reduce -----
__global__ __launch_bounds__(256) void gat_proj(
    const float* __restrict__ x, const float* __restrict__ W,
    const float* __restrict__ a, __hip_bfloat16* __restrict__ zT,
    float* __restrict__ si, float* __restrict__ sj,
    unsigned* __restrict__ mx) {
  __shared__ float wmx[4][2];
  const int lane = threadIdx.x & 63;
  const int wave = threadIdx.x >> 6;
  const int rowbase = blockIdx.x * 16 + wave * 4;  // 4 rows per wave, lane = col
  float acc[4] = {0.f, 0.f, 0.f, 0.f};
  for (int k = 0; k < DIN; k += 4) {
    const float w0 = W[(k + 0) * DOUT + lane];
    const float w1 = W[(k + 1) * DOUT + lane];
    const float w2 = W[(k + 2) * DOUT + lane];
    const float w3 = W[(k + 3) * DOUT + lane];
#pragma unroll
    for (int r = 0; r < 4; ++r) {
      const float4 xv = *reinterpret_cast<const float4*>(&x[(size_t)(rowbase + r) * DIN + k]);
      acc[r] += xv.x * w0 + xv.y * w1 + xv.z * w2 + xv.w * w3;
    }
  }
  const float a1l = a[lane];
  const float a2l = a[DOUT + lane];
  float wm1 = -1e30f, wm2 = -1e30f;
#pragma unroll
  for (int r = 0; r < 4; ++r) {
    const int row = rowbase + r;
    zT[(size_t)lane * N + row] = __float2bfloat16(acc[r]);
    float v1 = acc[r] * a1l;
    float v2 = acc[r] * a2l;
#pragma unroll
    for (int m = 1; m < 64; m <<= 1) {
      v1 += __shfl_xor(v1, m);
      v2 += __shfl_xor(v2, m);
    }
    if (lane == 0) { si[row] = v1; sj[row] = v2; }
    wm1 = fmaxf(wm1, v1);
    wm2 = fmaxf(wm2, v2);
  }
  if (lane == 0) { wmx[wave][0] = wm1; wmx[wave][1] = wm2; }
  __syncthreads();
  if (threadIdx.x == 0) {
    float M1 = fmaxf(fmaxf(wmx[0][0], wmx[1][0]), fmaxf(wmx[2][0], wmx[3][0]));
    float M2 = fmaxf(fmaxf(wmx[0][1], wmx[1][1]), fmaxf(wmx[2][1], wmx[3][1]));
    atomicMax(mx + 0, fkey(M1));
    atomicMax(mx + 1, fkey(M2));
  }
}

// ---- kernel 2: FUSED adj->bits (coalesced+ballot) + mask+exp + P@z (MFMA) --
// grid = NITILES*JSPLIT = 2048 blocks of 256 (4 waves x 16 rows).
// Prologue: wave reads its own 16 adj rows x 512 cols perfectly coalesced
// (lane c -> col w*64+c, 256B/inst), ballot packs 64 cols -> u64; each lane
// keeps only its fragment-aligned bits (4 x u32, compile-time indexed).
// K-loop: zero scattered loads except L2-resident zT; fully unrolled.
__global__ __launch_bounds__(256, 6) void gat_main(
    const int* __restrict__ adj, const float* __restrict__ si,
    const float* __restrict__ sj, const __hip_bfloat16* __restrict__ zT,
    const unsigned* __restrict__ mx, float* __restrict__ pnum,
    float* __restrict__ pden) {
  const int lane = threadIdx.x & 63;
  const int wave = threadIdx.x >> 6;
  const int itile = blockIdx.x % NITILES;
  const int jchunk = blockIdx.x / NITILES;
  const int r16 = lane & 15;
  const int kgrp = lane >> 4;
  const int row = itile * 64 + wave * 16 + r16;
  const int jbase = jchunk * JSPAN;

  // ---- prologue: coalesced adj tile -> per-lane fragment-aligned mask bits
  // bm_p bits: step it = p*4+sub -> byte (bm_p >> (sub*8)) & 0xFF
  // (byte e = col jbase + it*32 + kgrp*8 + e of row r16)
  unsigned bm0 = 0, bm1 = 0, bm2 = 0, bm3 = 0;
  {
    const int* __restrict__ abase =
        adj + (size_t)(itile * 64 + wave * 16) * N + jbase;
#pragma unroll 1
    for (int rr = 0; rr < 16; ++rr) {
      const int* __restrict__ ar = abase + (size_t)rr * N;
#pragma unroll
      for (int w = 0; w < 8; ++w) {  // u64 word w = cols w*64..w*64+63
        const int v = ar[w * 64 + lane];
        const unsigned long long m = __ballot(v > 0);
        const unsigned byte0 = (unsigned)(m >> (kgrp * 8)) & 0xffu;         // step 2w
        const unsigned byte1 = (unsigned)(m >> (32 + kgrp * 8)) & 0xffu;    // step 2w+1
        const unsigned contrib = (byte0 | (byte1 << 8)) << ((w & 1) * 16);
        if (r16 == rr) {
          if ((w >> 1) == 0) bm0 |= contrib;
          else if ((w >> 1) == 1) bm1 |= contrib;
          else if ((w >> 1) == 2) bm2 |= contrib;
          else bm3 |= contrib;
        }
      }
    }
  }

  const float tC = fdec(mx[0]) + fdec(mx[1]);
  const float C = tC > 0.f ? tC : LEAKY * tC;
  const float sir = si[row];

  const float* __restrict__ sp = sj + jbase + kgrp * 8;
  const __hip_bfloat16* __restrict__ zb0 = zT + (size_t)r16 * N + jbase + kgrp * 8;
  const __hip_bfloat16* __restrict__ zb1 = zb0 + (size_t)16 * N;
  const __hip_bfloat16* __restrict__ zb2 = zb0 + (size_t)32 * N;
  const __hip_bfloat16* __restrict__ zb3 = zb0 + (size_t)48 * N;

  f32x4 acc0 = {0.f, 0.f, 0.f, 0.f};
  f32x4 acc1 = acc0, acc2 = acc0, acc3 = acc0;
  float dacc = 0.f;

#pragma unroll
  for (int ph = 0; ph < 4; ++ph) {
    const unsigned bmp = (ph == 0) ? bm0 : (ph == 1) ? bm1 : (ph == 2) ? bm2 : bm3;
#pragma unroll
    for (int sub = 0; sub < 4; ++sub) {
      const int it = ph * 4 + sub;           // compile-time
      const unsigned bits = (bmp >> (sub * 8)) & 0xffu;

      const bf16x8 b0 = *reinterpret_cast<const bf16x8*>(zb0 + it * 32);
      const bf16x8 b1 = *reinterpret_cast<const bf16x8*>(zb1 + it * 32);
      const bf16x8 b2 = *reinterpret_cast<const bf16x8*>(zb2 + it * 32);
      const bf16x8 b3 = *reinterpret_cast<const bf16x8*>(zb3 + it * 32);
      const float4 s0 = *reinterpret_cast<const float4*>(sp + it * 32);
      const float4 s1 = *reinterpret_cast<const float4*>(sp + it * 32 + 4);

      float p0, p1, p2, p3, p4, p5, p6, p7, t;
      t = sir + s0.x; t = fmaxf(t, LEAKY * t); p0 = (bits & 1u)   ? __expf(t - C) : 0.f;
      t = sir + s0.y; t = fmaxf(t, LEAKY * t); p1 = (bits & 2u)   ? __expf(t - C) : 0.f;
      t = sir + s0.z; t = fmaxf(t, LEAKY * t); p2 = (bits & 4u)   ? __expf(t - C) : 0.f;
      t = sir + s0.w; t = fmaxf(t, LEAKY * t); p3 = (bits & 8u)   ? __expf(t - C) : 0.f;
      t = sir + s1.x; t = fmaxf(t, LEAKY * t); p4 = (bits & 16u)  ? __expf(t - C) : 0.f;
      t = sir + s1.y; t = fmaxf(t, LEAKY * t); p5 = (bits & 32u)  ? __expf(t - C) : 0.f;
      t = sir + s1.z; t = fmaxf(t, LEAKY * t); p6 = (bits & 64u)  ? __expf(t - C) : 0.f;
      t = sir + s1.w; t = fmaxf(t, LEAKY * t); p7 = (bits & 128u) ? __expf(t - C) : 0.f;

      dacc += ((p0 + p1) + (p2 + p3)) + ((p4 + p5) + (p6 + p7));

      bf16x8 afr;
      afr[0] = f2bf(p0); afr[1] = f2bf(p1); afr[2] = f2bf(p2); afr[3] = f2bf(p3);
      afr[4] = f2bf(p4); afr[5] = f2bf(p5); afr[6] = f2bf(p6); afr[7] = f2bf(p7);

      acc0 = __builtin_amdgcn_mfma_f32_16x16x32_bf16(afr, b0, acc0, 0, 0, 0);
      acc1 = __builtin_amdgcn_mfma_f32_16x16x32_bf16(afr, b1, acc1, 0, 0, 0);
      acc2 = __builtin_amdgcn_mfma_f32_16x16x32_bf16(afr, b2, acc2, 0, 0, 0);
      acc3 = __builtin_amdgcn_mfma_f32_16x16x32_bf16(afr, b3, acc3, 0, 0, 0);
    }
  }

  // denominator: combine the 4 k-groups holding the same row
  dacc += __shfl_xor(dacc, 16);
  dacc += __shfl_xor(dacc, 32);
  if (lane < 16) pden[(size_t)jchunk * N + row] = dacc;

  // C/D layout (16x16x32): col = lane&15, row = (lane>>4)*4 + reg
  float* np = pnum + ((size_t)jchunk * N + (size_t)itile * 64 + wave * 16) * DOUT;
  const f32x4 accs[4] = {acc0, acc1, acc2, acc3};
#pragma unroll
  for (int dt = 0; dt < 4; ++dt) {
#pragma unroll
    for (int r = 0; r < 4; ++r) {
      np[(kgrp * 4 + r) * DOUT + dt * 16 + r16] = accs[dt][r];
    }
  }
}

// ---- kernel 3: combine partials, divide, bias, relu ------------------------
__global__ __launch_bounds__(256) void gat_combine(
    const float* __restrict__ pnum, const float* __restrict__ pden,
    const float* __restrict__ b, float* __restrict__ out) {
  const int idx = blockIdx.x * 256 + threadIdx.x;
  const int row = idx >> 6;
  const int d = idx & 63;
  float num = 0.f, den = 0.f;
#pragma unroll
  for (int s = 0; s < JSPLIT; ++s) num += pnum[(size_t)s * N * DOUT + idx];
#pragma unroll
  for (int s = 0; s < JSPLIT; ++s) den += pden[(size_t)s * N + row];
  const float o = num / den + b[d];
  out[idx] = o > 0.f ? o : 0.f;
}

extern "C" void kernel_launch(void* const* d_in, const int* in_sizes, int n_in,
                              void* d_out, int out_size, void* d_ws, size_t ws_size,
                              hipStream_t stream) {
  const float* x = (const float*)d_in[0];
  const int* adj = (const int*)d_in[1];
  const float* W = (const float*)d_in[2];
  const float* a = (const float*)d_in[3];
  const float* b = (const float*)d_in[4];
  float* out = (float*)d_out;
  char* ws = (char*)d_ws;

  __hip_bfloat16* zT = (__hip_bfloat16*)(ws + OFF_ZT);
  float* si = (float*)(ws + OFF_SI);
  float* sj = (float*)(ws + OFF_SJ);
  unsigned* mx = (unsigned*)(ws + OFF_MAX);
  float* pden = (float*)(ws + OFF_PDEN);
  float* pnum = (float*)(ws + OFF_PNUM);

  gat_proj<<<dim3(N / 16), dim3(256), 0, stream>>>(x, W, a, zT, si, sj, mx);
  gat_main<<<dim3(NITILES * JSPLIT), dim3(256), 0, stream>>>(adj, si, sj, zT, mx,
                                                             pnum, pden);
  gat_combine<<<dim3((N * DOUT) / 256), dim3(256), 0, stream>>>(pnum, pden, b, out);
}

// Round 10
// 438.373 us; speedup vs baseline: 1.1374x; 1.0970x over previous
//
#include <hip/hip_runtime.h>
#include <hip/hip_bf16.h>

#define N 8192
#define DIN 256
#define DOUT 64
#define JSPLIT 32
#define JSPAN (N / JSPLIT)      // 256
#define KSTEPS (JSPAN / 32)     // 8
#define NITILES (N / 64)        // 128
#define LEAKY 0.2f

typedef __attribute__((ext_vector_type(8))) short bf16x8;
typedef __attribute__((ext_vector_type(4))) float f32x4;

// workspace layout (aligned slices)
#define OFF_ZT   ((size_t)0)                               // DOUT*N*2  = 1 MiB
#define OFF_SI   (OFF_ZT + (size_t)DOUT * N * 2)           // N*4
#define OFF_SJ   (OFF_SI + (size_t)N * 4)                  // N*4
#define OFF_MAX  (OFF_SJ + (size_t)N * 4)                  // 256 (2 uints used)
#define OFF_PDEN (OFF_MAX + 256)                           // JSPLIT*N*4 = 1 MiB
#define OFF_PNUM (OFF_PDEN + (size_t)JSPLIT * N * 4)       // JSPLIT*N*DOUT*4 = 64 MiB

static __device__ __forceinline__ short f2bf(float f) {
  union { __hip_bfloat16 h; short s; } u;
  u.h = __float2bfloat16(f);
  return u.s;
}

// monotone float<->unsigned key for atomicMax (poison 0xAAAAAAAA decodes to
// +3.03e-13, provably below max of 8192 ~N(0,1) samples -> no init needed)
static __device__ __forceinline__ unsigned fkey(float f) {
  int b = __float_as_int(f);
  return (b < 0) ? ~(unsigned)b : ((unsigned)b | 0x80000000u);
}
static __device__ __forceinline__ float fdec(unsigned k) {
  int b = (k & 0x80000000u) ? (int)(k & 0x7fffffffu) : (int)~k;
  return __int_as_float(b);
}

// ---- kernel 1: z = x@W ; si = z@a1 ; sj = z@a2 ; zT(bf16) ; max-reduce -----
__global__ __launch_bounds__(256) void gat_proj(
    const float* __restrict__ x, const float* __restrict__ W,
    const float* __restrict__ a, __hip_bfloat16* __restrict__ zT,
    float* __restrict__ si, float* __restrict__ sj,
    unsigned* __restrict__ mx) {
  __shared__ float wmx[4][2];
  const int lane = threadIdx.x & 63;
  const int wave = threadIdx.x >> 6;
  const int rowbase = blockIdx.x * 16 + wave * 4;  // 4 rows per wave, lane = col
  float acc[4] = {0.f, 0.f, 0.f, 0.f};
  for (int k = 0; k < DIN; k += 4) {
    const float w0 = W[(k + 0) * DOUT + lane];
    const float w1 = W[(k + 1) * DOUT + lane];
    const float w2 = W[(k + 2) * DOUT + lane];
    const float w3 = W[(k + 3) * DOUT + lane];
#pragma unroll
    for (int r = 0; r < 4; ++r) {
      const float4 xv = *reinterpret_cast<const float4*>(&x[(size_t)(rowbase + r) * DIN + k]);
      acc[r] += xv.x * w0 + xv.y * w1 + xv.z * w2 + xv.w * w3;
    }
  }
  const float a1l = a[lane];
  const float a2l = a[DOUT + lane];
  float wm1 = -1e30f, wm2 = -1e30f;
#pragma unroll
  for (int r = 0; r < 4; ++r) {
    const int row = rowbase + r;
    zT[(size_t)lane * N + row] = __float2bfloat16(acc[r]);
    float v1 = acc[r] * a1l;
    float v2 = acc[r] * a2l;
#pragma unroll
    for (int m = 1; m < 64; m <<= 1) {
      v1 += __shfl_xor(v1, m);
      v2 += __shfl_xor(v2, m);
    }
    if (lane == 0) { si[row] = v1; sj[row] = v2; }
    wm1 = fmaxf(wm1, v1);
    wm2 = fmaxf(wm2, v2);
  }
  if (lane == 0) { wmx[wave][0] = wm1; wmx[wave][1] = wm2; }
  __syncthreads();
  if (threadIdx.x == 0) {
    float M1 = fmaxf(fmaxf(wmx[0][0], wmx[1][0]), fmaxf(wmx[2][0], wmx[3][0]));
    float M2 = fmaxf(fmaxf(wmx[0][1], wmx[1][1]), fmaxf(wmx[2][1], wmx[3][1]));
    atomicMax(mx + 0, fkey(M1));
    atomicMax(mx + 1, fkey(M2));
  }
}

// ---- kernel 2: FUSED adj->bits + mask+exp + P@z (MFMA), LDS-staged B ------
// grid = NITILES*JSPLIT = 4096 blocks of 256 (4 waves x 16 rows), JSPAN=256.
// The zT tile (64x256 bf16 = 32KB) is staged coalesced into LDS once; the
// MFMA B-fragments then come from ds_read_b128 instead of 16-line 16KB-stride
// L2 gathers (the invariant bottleneck of r4/r6/r7). Row stride 264 bf16 =
// 528B (16B-aligned, 132 dwords -> uniform 8-slot bank starts, ~minimal for
// b128). adj prologue: coalesced + ballot, fully unrolled (pipelined vmcnt).
__global__ __launch_bounds__(256, 4) void gat_main(
    const int* __restrict__ adj, const float* __restrict__ si,
    const float* __restrict__ sj, const __hip_bfloat16* __restrict__ zT,
    const unsigned* __restrict__ mx, float* __restrict__ pnum,
    float* __restrict__ pden) {
  __shared__ short lds_z[64][264];
  const int tid = threadIdx.x;
  const int lane = tid & 63;
  const int wave = tid >> 6;
  const int itile = blockIdx.x % NITILES;
  const int jchunk = blockIdx.x / NITILES;
  const int r16 = lane & 15;
  const int kgrp = lane >> 4;
  const int row = itile * 64 + wave * 16 + r16;
  const int jbase = jchunk * JSPAN;

  // ---- stage zT tile into LDS (b128, fully coalesced: 32 lanes = 1 row) ----
  {
    const int r = tid >> 5;          // 0..7
    const int cb = (tid & 31) * 8;   // bf16 col, 16B granularity
#pragma unroll
    for (int rr = 0; rr < 8; ++rr) {
      const int d = rr * 8 + r;
      const bf16x8 v =
          *reinterpret_cast<const bf16x8*>(zT + (size_t)d * N + jbase + cb);
      *reinterpret_cast<bf16x8*>(&lds_z[d][cb]) = v;
    }
  }

  // ---- adj -> per-lane fragment-aligned mask bits (coalesced + ballot) ----
  // step it = 2w+sub covers cols jbase+it*32..+31; byte for (it,kgrp):
  // bits = (bm_{it>>2} >> ((it&3)*8)) & 0xFF
  unsigned bm0 = 0, bm1 = 0;
  {
    const int* __restrict__ abase =
        adj + (size_t)(itile * 64 + wave * 16) * N + jbase;
#pragma unroll
    for (int rr = 0; rr < 16; ++rr) {
#pragma unroll
      for (int w = 0; w < 4; ++w) {
        const int v = abase[(size_t)rr * N + w * 64 + lane];
        const unsigned long long m = __ballot(v > 0);
        const unsigned byte0 = (unsigned)(m >> (kgrp * 8)) & 0xffu;
        const unsigned byte1 = (unsigned)(m >> (32 + kgrp * 8)) & 0xffu;
        const unsigned contrib = (byte0 | (byte1 << 8)) << ((w & 1) * 16);
        if (r16 == rr) {
          if (w < 2) bm0 |= contrib; else bm1 |= contrib;
        }
      }
    }
  }
  __syncthreads();

  const float tC = fdec(mx[0]) + fdec(mx[1]);
  const float C = tC > 0.f ? tC : LEAKY * tC;
  const float sir = si[row];
  const float* __restrict__ sp = sj + jbase + kgrp * 8;

  f32x4 acc0 = {0.f, 0.f, 0.f, 0.f};
  f32x4 acc1 = acc0, acc2 = acc0, acc3 = acc0;
  float dacc = 0.f;

#pragma unroll
  for (int it = 0; it < KSTEPS; ++it) {
    const unsigned bmp = (it < 4) ? bm0 : bm1;
    const unsigned bits = (bmp >> ((it & 3) * 8)) & 0xffu;
    const int col = it * 32 + kgrp * 8;

    const bf16x8 b0 = *reinterpret_cast<const bf16x8*>(&lds_z[r16][col]);
    const bf16x8 b1 = *reinterpret_cast<const bf16x8*>(&lds_z[16 + r16][col]);
    const bf16x8 b2 = *reinterpret_cast<const bf16x8*>(&lds_z[32 + r16][col]);
    const bf16x8 b3 = *reinterpret_cast<const bf16x8*>(&lds_z[48 + r16][col]);
    const float4 s0 = *reinterpret_cast<const float4*>(sp + it * 32);
    const float4 s1 = *reinterpret_cast<const float4*>(sp + it * 32 + 4);

    float p0, p1, p2, p3, p4, p5, p6, p7, t;
    t = sir + s0.x; t = fmaxf(t, LEAKY * t); p0 = (bits & 1u)   ? __expf(t - C) : 0.f;
    t = sir + s0.y; t = fmaxf(t, LEAKY * t); p1 = (bits & 2u)   ? __expf(t - C) : 0.f;
    t = sir + s0.z; t = fmaxf(t, LEAKY * t); p2 = (bits & 4u)   ? __expf(t - C) : 0.f;
    t = sir + s0.w; t = fmaxf(t, LEAKY * t); p3 = (bits & 8u)   ? __expf(t - C) : 0.f;
    t = sir + s1.x; t = fmaxf(t, LEAKY * t); p4 = (bits & 16u)  ? __expf(t - C) : 0.f;
    t = sir + s1.y; t = fmaxf(t, LEAKY * t); p5 = (bits & 32u)  ? __expf(t - C) : 0.f;
    t = sir + s1.z; t = fmaxf(t, LEAKY * t); p6 = (bits & 64u)  ? __expf(t - C) : 0.f;
    t = sir + s1.w; t = fmaxf(t, LEAKY * t); p7 = (bits & 128u) ? __expf(t - C) : 0.f;

    dacc += ((p0 + p1) + (p2 + p3)) + ((p4 + p5) + (p6 + p7));

    bf16x8 afr;
    afr[0] = f2bf(p0); afr[1] = f2bf(p1); afr[2] = f2bf(p2); afr[3] = f2bf(p3);
    afr[4] = f2bf(p4); afr[5] = f2bf(p5); afr[6] = f2bf(p6); afr[7] = f2bf(p7);

    acc0 = __builtin_amdgcn_mfma_f32_16x16x32_bf16(afr, b0, acc0, 0, 0, 0);
    acc1 = __builtin_amdgcn_mfma_f32_16x16x32_bf16(afr, b1, acc1, 0, 0, 0);
    acc2 = __builtin_amdgcn_mfma_f32_16x16x32_bf16(afr, b2, acc2, 0, 0, 0);
    acc3 = __builtin_amdgcn_mfma_f32_16x16x32_bf16(afr, b3, acc3, 0, 0, 0);
  }

  // denominator: combine the 4 k-groups holding the same row
  dacc += __shfl_xor(dacc, 16);
  dacc += __shfl_xor(dacc, 32);
  if (lane < 16) pden[(size_t)jchunk * N + row] = dacc;

  // C/D layout (16x16x32): col = lane&15, row = (lane>>4)*4 + reg
  float* np = pnum + ((size_t)jchunk * N + (size_t)itile * 64 + wave * 16) * DOUT;
  const f32x4 accs[4] = {acc0, acc1, acc2, acc3};
#pragma unroll
  for (int dt = 0; dt < 4; ++dt) {
#pragma unroll
    for (int r = 0; r < 4; ++r) {
      np[(kgrp * 4 + r) * DOUT + dt * 16 + r16] = accs[dt][r];
    }
  }
}

// ---- kernel 3: combine partials, divide, bias, relu ------------------------
__global__ __launch_bounds__(256) void gat_combine(
    const float* __restrict__ pnum, const float* __restrict__ pden,
    const float* __restrict__ b, float* __restrict__ out) {
  const int idx = blockIdx.x * 256 + threadIdx.x;
  const int row = idx >> 6;
  const int d = idx & 63;
  float num = 0.f, den = 0.f;
#pragma unroll
  for (int s = 0; s < JSPLIT; ++s) num += pnum[(size_t)s * N * DOUT + idx];
#pragma unroll
  for (int s = 0; s < JSPLIT; ++s) den += pden[(size_t)s * N + row];
  const float o = num / den + b[d];
  out[idx] = o > 0.f ? o : 0.f;
}

extern "C" void kernel_launch(void* const* d_in, const int* in_sizes, int n_in,
                              void* d_out, int out_size, void* d_ws, size_t ws_size,
                              hipStream_t stream) {
  const float* x = (const float*)d_in[0];
  const int* adj = (const int*)d_in[1];
  const float* W = (const float*)d_in[2];
  const float* a = (const float*)d_in[3];
  const float* b = (const float*)d_in[4];
  float* out = (float*)d_out;
  char* ws = (char*)d_ws;

  __hip_bfloat16* zT = (__hip_bfloat16*)(ws + OFF_ZT);
  float* si = (float*)(ws + OFF_SI);
  float* sj = (float*)(ws + OFF_SJ);
  unsigned* mx = (unsigned*)(ws + OFF_MAX);
  float* pden = (float*)(ws + OFF_PDEN);
  float* pnum = (float*)(ws + OFF_PNUM);

  gat_proj<<<dim3(N / 16), dim3(256), 0, stream>>>(x, W, a, zT, si, sj, mx);
  gat_main<<<dim3(NITILES * JSPLIT), dim3(256), 0, stream>>>(adj, si, sj, zT, mx,
                                                             pnum, pden);
  gat_combine<<<dim3((N * DOUT) / 256), dim3(256), 0, stream>>>(pnum, pden, b, out);
}

// Round 12
// 429.597 us; speedup vs baseline: 1.1607x; 1.0204x over previous
//
#include <hip/hip_runtime.h>
#include <hip/hip_bf16.h>

#define N 8192
#define DIN 256
#define DOUT 64
#define JSPLIT 32
#define JSPAN (N / JSPLIT)      // 256
#define KSTEPS (JSPAN / 32)     // 8
#define NITILES (N / 64)        // 128
#define LEAKY 0.2f

typedef __attribute__((ext_vector_type(8))) short bf16x8;
typedef __attribute__((ext_vector_type(4))) float f32x4;

// workspace layout (aligned slices)
#define OFF_ZT   ((size_t)0)                               // DOUT*N*2  = 1 MiB
#define OFF_SI   (OFF_ZT + (size_t)DOUT * N * 2)           // N*4
#define OFF_SJ   (OFF_SI + (size_t)N * 4)                  // N*4
#define OFF_MAX  (OFF_SJ + (size_t)N * 4)                  // 256 (2 uints used)
#define OFF_PDEN (OFF_MAX + 256)                           // JSPLIT*N*4 = 1 MiB
#define OFF_PNUM (OFF_PDEN + (size_t)JSPLIT * N * 4)       // JSPLIT*N*DOUT*4 = 64 MiB

static __device__ __forceinline__ short f2bf(float f) {
  union { __hip_bfloat16 h; short s; } u;
  u.h = __float2bfloat16(f);
  return u.s;
}

// monotone float<->unsigned key for atomicMax (poison 0xAAAAAAAA decodes to
// +3.03e-13, provably below max of 8192 ~N(0,1) samples -> no init needed)
static __device__ __forceinline__ unsigned fkey(float f) {
  int b = __float_as_int(f);
  return (b < 0) ? ~(unsigned)b : ((unsigned)b | 0x80000000u);
}
static __device__ __forceinline__ float fdec(unsigned k) {
  int b = (k & 0x80000000u) ? (int)(k & 0x7fffffffu) : (int)~k;
  return __int_as_float(b);
}

// ---- kernel 1: z = x@W ; si = z@a1 ; sj = z@a2 ; zT(bf16) ; max-reduce -----
__global__ __launch_bounds__(256) void gat_proj(
    const float* __restrict__ x, const float* __restrict__ W,
    const float* __restrict__ a, __hip_bfloat16* __restrict__ zT,
    float* __restrict__ si, float* __restrict__ sj,
    unsigned* __restrict__ mx) {
  __shared__ float wmx[4][2];
  const int lane = threadIdx.x & 63;
  const int wave = threadIdx.x >> 6;
  const int rowbase = blockIdx.x * 16 + wave * 4;  // 4 rows per wave, lane = col
  float acc[4] = {0.f, 0.f, 0.f, 0.f};
  for (int k = 0; k < DIN; k += 4) {
    const float w0 = W[(k + 0) * DOUT + lane];
    const float w1 = W[(k + 1) * DOUT + lane];
    const float w2 = W[(k + 2) * DOUT + lane];
    const float w3 = W[(k + 3) * DOUT + lane];
#pragma unroll
    for (int r = 0; r < 4; ++r) {
      const float4 xv = *reinterpret_cast<const float4*>(&x[(size_t)(rowbase + r) * DIN + k]);
      acc[r] += xv.x * w0 + xv.y * w1 + xv.z * w2 + xv.w * w3;
    }
  }
  const float a1l = a[lane];
  const float a2l = a[DOUT + lane];
  float wm1 = -1e30f, wm2 = -1e30f;
#pragma unroll
  for (int r = 0; r < 4; ++r) {
    const int row = rowbase + r;
    zT[(size_t)lane * N + row] = __float2bfloat16(acc[r]);
    float v1 = acc[r] * a1l;
    float v2 = acc[r] * a2l;
#pragma unroll
    for (int m = 1; m < 64; m <<= 1) {
      v1 += __shfl_xor(v1, m);
      v2 += __shfl_xor(v2, m);
    }
    if (lane == 0) { si[row] = v1; sj[row] = v2; }
    wm1 = fmaxf(wm1, v1);
    wm2 = fmaxf(wm2, v2);
  }
  if (lane == 0) { wmx[wave][0] = wm1; wmx[wave][1] = wm2; }
  __syncthreads();
  if (threadIdx.x == 0) {
    float M1 = fmaxf(fmaxf(wmx[0][0], wmx[1][0]), fmaxf(wmx[2][0], wmx[3][0]));
    float M2 = fmaxf(fmaxf(wmx[0][1], wmx[1][1]), fmaxf(wmx[2][1], wmx[3][1]));
    atomicMax(mx + 0, fkey(M1));
    atomicMax(mx + 1, fkey(M2));
  }
}

// ---- kernel 2: FUSED adj->bits + mask+exp + P@z (MFMA), swizzled LDS B -----
// grid = NITILES*JSPLIT = 4096 blocks of 256 (4 waves x 16 rows), JSPAN=256.
// (1) LDS tile exact 32KB [64][256] with XOR swizzle (byte ^= (row&7)<<4;
// (dt*16+r16)&7 == r16&7 so one XOR per lane) -> 5 blocks/CU; (2) adj
// prologue loads batched 32-deep into registers (static indexing) before
// ballots -> ~32 outstanding HBM loads per wave instead of the VGPR-starved
// trickle that serialized r10's prologue.
__global__ __launch_bounds__(256, 5) void gat_main(
    const int* __restrict__ adj, const float* __restrict__ si,
    const float* __restrict__ sj, const __hip_bfloat16* __restrict__ zT,
    const unsigned* __restrict__ mx, float* __restrict__ pnum,
    float* __restrict__ pden) {
  __shared__ short lds_z[64][256];
  const int tid = threadIdx.x;
  const int lane = tid & 63;
  const int wave = tid >> 6;
  const int itile = blockIdx.x % NITILES;
  const int jchunk = blockIdx.x / NITILES;
  const int r16 = lane & 15;
  const int kgrp = lane >> 4;
  const int row = itile * 64 + wave * 16 + r16;
  const int jbase = jchunk * JSPAN;

  // ---- stage zT tile (L2-resident) into swizzled LDS (b128 coalesced) ----
  {
    const int rgrp = tid >> 5;          // 0..7
    const int cslot = (tid & 31) * 16;  // byte col within 512B row
    char* ldsb = (char*)&lds_z[0][0];
#pragma unroll
    for (int rr = 0; rr < 8; ++rr) {
      const int d = rr * 8 + rgrp;
      const bf16x8 v = *reinterpret_cast<const bf16x8*>(
          zT + (size_t)d * N + jbase + (tid & 31) * 8);
      *reinterpret_cast<bf16x8*>(ldsb + d * 512 + (cslot ^ ((d & 7) << 4))) = v;
    }
  }

  // ---- adj -> per-lane fragment-aligned mask bits, 32-deep load batches ----
  // step it covers cols jbase+it*32..+31; bits for (it,kgrp) =
  // ((it<4?bm0:bm1) >> ((it&3)*8)) & 0xFF
  unsigned bm0 = 0, bm1 = 0;
  const int* __restrict__ abase =
      adj + (size_t)(itile * 64 + wave * 16) * N + jbase;
  {
    int va[32];
#pragma unroll
    for (int i = 0; i < 32; ++i)
      va[i] = abase[(size_t)(i >> 2) * N + (i & 3) * 64 + lane];
#pragma unroll
    for (int i = 0; i < 32; ++i) {
      const int rr = i >> 2, w = i & 3;
      const unsigned long long m = __ballot(va[i] > 0);
      const unsigned b0 = (unsigned)(m >> (kgrp * 8)) & 0xffu;
      const unsigned b1 = (unsigned)(m >> (32 + kgrp * 8)) & 0xffu;
      const unsigned contrib = (b0 | (b1 << 8)) << ((w & 1) * 16);
      if (r16 == rr) { if (w < 2) bm0 |= contrib; else bm1 |= contrib; }
    }
#pragma unroll
    for (int i = 0; i < 32; ++i)
      va[i] = abase[(size_t)(8 + (i >> 2)) * N + (i & 3) * 64 + lane];
#pragma unroll
    for (int i = 0; i < 32; ++i) {
      const int rr = 8 + (i >> 2), w = i & 3;
      const unsigned long long m = __ballot(va[i] > 0);
      const unsigned b0 = (unsigned)(m >> (kgrp * 8)) & 0xffu;
      const unsigned b1 = (unsigned)(m >> (32 + kgrp * 8)) & 0xffu;
      const unsigned contrib = (b0 | (b1 << 8)) << ((w & 1) * 16);
      if (r16 == rr) { if (w < 2) bm0 |= contrib; else bm1 |= contrib; }
    }
  }
  __syncthreads();

  const float tC = fdec(mx[0]) + fdec(mx[1]);
  const float C = tC > 0.f ? tC : LEAKY * tC;
  const float sir = si[row];
  const float* __restrict__ sp = sj + jbase + kgrp * 8;
  const char* __restrict__ zr0 = (const char*)&lds_z[0][0] + r16 * 512;
  const int swz = (r16 & 7) << 4;

  f32x4 acc0 = {0.f, 0.f, 0.f, 0.f};
  f32x4 acc1 = acc0, acc2 = acc0, acc3 = acc0;
  float dacc = 0.f;

#pragma unroll
  for (int it = 0; it < KSTEPS; ++it) {
    const unsigned bits = ((it < 4 ? bm0 : bm1) >> ((it & 3) * 8)) & 0xffu;
    const int cb = (it * 64 + kgrp * 16) ^ swz;

    const bf16x8 b0 = *reinterpret_cast<const bf16x8*>(zr0 + cb);
    const bf16x8 b1 = *reinterpret_cast<const bf16x8*>(zr0 + 16 * 512 + cb);
    const bf16x8 b2 = *reinterpret_cast<const bf16x8*>(zr0 + 32 * 512 + cb);
    const bf16x8 b3 = *reinterpret_cast<const bf16x8*>(zr0 + 48 * 512 + cb);
    const float4 s0 = *reinterpret_cast<const float4*>(sp + it * 32);
    const float4 s1 = *reinterpret_cast<const float4*>(sp + it * 32 + 4);

    float p0, p1, p2, p3, p4, p5, p6, p7, t;
    t = sir + s0.x; t = fmaxf(t, LEAKY * t); p0 = (bits & 1u)   ? __expf(t - C) : 0.f;
    t = sir + s0.y; t = fmaxf(t, LEAKY * t); p1 = (bits & 2u)   ? __expf(t - C) : 0.f;
    t = sir + s0.z; t = fmaxf(t, LEAKY * t); p2 = (bits & 4u)   ? __expf(t - C) : 0.f;
    t = sir + s0.w; t = fmaxf(t, LEAKY * t); p3 = (bits & 8u)   ? __expf(t - C) : 0.f;
    t = sir + s1.x; t = fmaxf(t, LEAKY * t); p4 = (bits & 16u)  ? __expf(t - C) : 0.f;
    t = sir + s1.y; t = fmaxf(t, LEAKY * t); p5 = (bits & 32u)  ? __expf(t - C) : 0.f;
    t = sir + s1.z; t = fmaxf(t, LEAKY * t); p6 = (bits & 64u)  ? __expf(t - C) : 0.f;
    t = sir + s1.w; t = fmaxf(t, LEAKY * t); p7 = (bits & 128u) ? __expf(t - C) : 0.f;

    dacc += ((p0 + p1) + (p2 + p3)) + ((p4 + p5) + (p6 + p7));

    bf16x8 afr;
    afr[0] = f2bf(p0); afr[1] = f2bf(p1); afr[2] = f2bf(p2); afr[3] = f2bf(p3);
    afr[4] = f2bf(p4); afr[5] = f2bf(p5); afr[6] = f2bf(p6); afr[7] = f2bf(p7);

    acc0 = __builtin_amdgcn_mfma_f32_16x16x32_bf16(afr, b0, acc0, 0, 0, 0);
    acc1 = __builtin_amdgcn_mfma_f32_16x16x32_bf16(afr, b1, acc1, 0, 0, 0);
    acc2 = __builtin_amdgcn_mfma_f32_16x16x32_bf16(afr, b2, acc2, 0, 0, 0);
    acc3 = __builtin_amdgcn_mfma_f32_16x16x32_bf16(afr, b3, acc3, 0, 0, 0);
  }

  // denominator: combine the 4 k-groups holding the same row
  dacc += __shfl_xor(dacc, 16);
  dacc += __shfl_xor(dacc, 32);
  if (lane < 16) pden[(size_t)jchunk * N + row] = dacc;

  // C/D layout (16x16x32): col = lane&15, row = (lane>>4)*4 + reg
  float* np = pnum + ((size_t)jchunk * N + (size_t)itile * 64 + wave * 16) * DOUT;
  const f32x4 accs[4] = {acc0, acc1, acc2, acc3};
#pragma unroll
  for (int dt = 0; dt < 4; ++dt) {
#pragma unroll
    for (int r = 0; r < 4; ++r) {
      np[(kgrp * 4 + r) * DOUT + dt * 16 + r16] = accs[dt][r];
    }
  }
}

// ---- kernel 3: combine partials, divide, bias, relu ------------------------
__global__ __launch_bounds__(256) void gat_combine(
    const float* __restrict__ pnum, const float* __restrict__ pden,
    const float* __restrict__ b, float* __restrict__ out) {
  const int idx = blockIdx.x * 256 + threadIdx.x;
  const int row = idx >> 6;
  const int d = idx & 63;
  float num = 0.f, den = 0.f;
#pragma unroll
  for (int s = 0; s < JSPLIT; ++s) num += pnum[(size_t)s * N * DOUT + idx];
#pragma unroll
  for (int s = 0; s < JSPLIT; ++s) den += pden[(size_t)s * N + row];
  const float o = num / den + b[d];
  out[idx] = o > 0.f ? o : 0.f;
}

extern "C" void kernel_launch(void* const* d_in, const int* in_sizes, int n_in,
                              void* d_out, int out_size, void* d_ws, size_t ws_size,
                              hipStream_t stream) {
  const float* x = (const float*)d_in[0];
  const int* adj = (const int*)d_in[1];
  const float* W = (const float*)d_in[2];
  const float* a = (const float*)d_in[3];
  const float* b = (const float*)d_in[4];
  float* out = (float*)d_out;
  char* ws = (char*)d_ws;

  __hip_bfloat16* zT = (__hip_bfloat16*)(ws + OFF_ZT);
  float* si = (float*)(ws + OFF_SI);
  float* sj = (float*)(ws + OFF_SJ);
  unsigned* mx = (unsigned*)(ws + OFF_MAX);
  float* pden = (float*)(ws + OFF_PDEN);
  float* pnum = (float*)(ws + OFF_PNUM);

  gat_proj<<<dim3(N / 16), dim3(256), 0, stream>>>(x, W, a, zT, si, sj, mx);
  gat_main<<<dim3(NITILES * JSPLIT), dim3(256), 0, stream>>>(adj, si, sj, zT, mx,
                                                             pnum, pden);
  gat_combine<<<dim3((N * DOUT) / 256), dim3(256), 0, stream>>>(pnum, pden, b, out);
}